// Round 1
// baseline (496.032 us; speedup 1.0000x reference)
//
#include <hip/hip_runtime.h>

#define D 256
#define VOCAB 4096
#define NTOT 16384   // 16 * 32 * 32
#define N_OUT0 4194304  // 16*256*32*32

// ---------------- kernel 0: e_sq + gbest init ----------------
__global__ __launch_bounds__(64) void k_init(const float* __restrict__ emb,
                                             float* __restrict__ esq,
                                             unsigned long long* __restrict__ gbest) {
    const int v = blockIdx.x;
    const int lane = threadIdx.x;
    float4 e = *(const float4*)(emb + (size_t)v * D + lane * 4);
    float s = e.x * e.x + e.y * e.y + e.z * e.z + e.w * e.w;
#pragma unroll
    for (int m = 32; m >= 1; m >>= 1) s += __shfl_xor(s, m, 64);
    if (lane == 0) esq[v] = s;
    if (blockIdx.x < NTOT / 64) gbest[blockIdx.x * 64 + lane] = 0xFFFFFFFFFFFFFFFFULL;
}

// ---------------- kernel 1: distance GEMM + argmin ----------------
// grid 1024: blockIdx>>2 = n-tile (64 n), blockIdx&3 = v-split (1024 v)
// block 256 threads: 8(tn) x 32(tv), micro-tile 8n x 8v
__global__ __launch_bounds__(256) void k_argmin(const float* __restrict__ h,
                                                const float* __restrict__ emb,
                                                const float* __restrict__ esq,
                                                unsigned long long* __restrict__ gbest) {
    __shared__ float hT[16][64];    // [c][n]
    __shared__ float eT[16][256];   // [c][v]
    __shared__ unsigned long long red[64];

    const int tid = threadIdx.x;
    const int nt = blockIdx.x >> 2;
    const int vs = blockIdx.x & 3;
    const int n0 = nt * 64;
    const int b = n0 >> 10;
    const int p0 = n0 & 1023;
    const float* hb = h + (((size_t)b * D) << 10) + p0;  // + c*1024 + nn

    const int tn = tid & 7;
    const int tv = tid >> 3;

    float minv[8];
    int mini[8];
#pragma unroll
    for (int i = 0; i < 8; ++i) { minv[i] = 3.0e38f; mini[i] = 0; }

    const int scc = tid >> 4;        // h-stage: c within chunk
    const int snn = (tid * 4) & 63;  // h-stage: n within tile

    for (int vc = 0; vc < 4; ++vc) {
        const int v0 = vs * 1024 + vc * 256;
        float acc[8][8];
#pragma unroll
        for (int i = 0; i < 8; ++i)
#pragma unroll
            for (int j = 0; j < 8; ++j) acc[i][j] = 0.0f;

        for (int c0 = 0; c0 < D; c0 += 16) {
            // stage h tile: 16c x 64n (coalesced float4)
            float4 hv4 = *(const float4*)(hb + (size_t)(c0 + scc) * 1024 + snn);
            // stage e tile transposed: read row-major float4s, scatter to eT[c][v]
            const float* er = emb + (size_t)(v0 + tid) * D + c0;
            float4 e0 = *(const float4*)(er);
            float4 e1 = *(const float4*)(er + 4);
            float4 e2 = *(const float4*)(er + 8);
            float4 e3 = *(const float4*)(er + 12);
            *(float4*)&hT[scc][snn] = hv4;
            eT[0][tid] = e0.x;  eT[1][tid] = e0.y;  eT[2][tid] = e0.z;  eT[3][tid] = e0.w;
            eT[4][tid] = e1.x;  eT[5][tid] = e1.y;  eT[6][tid] = e1.z;  eT[7][tid] = e1.w;
            eT[8][tid] = e2.x;  eT[9][tid] = e2.y;  eT[10][tid] = e2.z; eT[11][tid] = e2.w;
            eT[12][tid] = e3.x; eT[13][tid] = e3.y; eT[14][tid] = e3.z; eT[15][tid] = e3.w;
            __syncthreads();
#pragma unroll
            for (int cc = 0; cc < 16; ++cc) {
                float4 a0 = *(const float4*)&hT[cc][tn * 8];
                float4 a1 = *(const float4*)&hT[cc][tn * 8 + 4];
                float4 b0 = *(const float4*)&eT[cc][tv * 8];
                float4 b1 = *(const float4*)&eT[cc][tv * 8 + 4];
                float av[8] = {a0.x, a0.y, a0.z, a0.w, a1.x, a1.y, a1.z, a1.w};
                float bv[8] = {b0.x, b0.y, b0.z, b0.w, b1.x, b1.y, b1.z, b1.w};
#pragma unroll
                for (int i = 0; i < 8; ++i)
#pragma unroll
                    for (int j = 0; j < 8; ++j)
                        acc[i][j] = fmaf(av[i], bv[j], acc[i][j]);
            }
            __syncthreads();
        }
        // epilogue: dist(n,v) = esq[v] - 2*dot  (+ ||h||^2, constant per n, omitted)
#pragma unroll
        for (int j = 0; j < 8; ++j) {
            int v = v0 + tv * 8 + j;
            float es = esq[v];
#pragma unroll
            for (int i = 0; i < 8; ++i) {
                float dv = es - 2.0f * acc[i][j];
                if (dv < minv[i]) { minv[i] = dv; mini[i] = v; }
            }
        }
    }

    // block-level reduce over the 32 tv groups, then global merge over v-splits
    if (tid < 64) red[tid] = 0xFFFFFFFFFFFFFFFFULL;
    __syncthreads();
#pragma unroll
    for (int i = 0; i < 8; ++i) {
        unsigned u = __float_as_uint(minv[i]);
        unsigned mask = (unsigned)((int)u >> 31) | 0x80000000u;  // monotonic float->uint
        u ^= mask;
        unsigned long long key = ((unsigned long long)u << 32) | (unsigned)mini[i];
        atomicMin(&red[tn * 8 + i], key);
    }
    __syncthreads();
    if (tid < 64) atomicMin(&gbest[n0 + tid], red[tid]);
}

// ---------------- kernel 2: gather z_q, write outputs, loss partials ----------------
// grid 512 blocks x 32 n each, block 256 (4 waves)
__global__ __launch_bounds__(256) void k_gather(const float* __restrict__ h,
                                                const float* __restrict__ emb,
                                                const unsigned long long* __restrict__ gbest,
                                                float* __restrict__ out0,
                                                float* __restrict__ out1,
                                                float* __restrict__ plsum) {
    __shared__ float zq[32][260];
    __shared__ float wred[4];
    const int tid = threadIdx.x;
    const int lane = tid & 63;
    const int w = tid >> 6;
    const int n0 = blockIdx.x * 32;
    const int b = n0 >> 10;
    const int p0 = n0 & 1023;

#pragma unroll
    for (int rr = 0; rr < 8; ++rr) {
        int r = w * 8 + rr;
        unsigned idx = (unsigned)(gbest[n0 + r] & 0xFFFFFFFFULL);
        float4 e4 = *(const float4*)(emb + (size_t)idx * D + lane * 4);
        *(float4*)&zq[r][lane * 4] = e4;
    }
    if (tid < 32) {
        unsigned idx = (unsigned)(gbest[n0 + tid] & 0xFFFFFFFFULL);
        out1[n0 + tid] = (float)idx;  // indices as float32 (flat f32 output buffer)
    }
    __syncthreads();

    float lsum = 0.0f;
    const size_t base = ((size_t)b * D) << 10;
#pragma unroll 4
    for (int it = 0; it < 32; ++it) {
        int c = it * 8 + (tid >> 5);
        int pp = tid & 31;
        float z = zq[pp][c];
        size_t g = base + ((size_t)c << 10) + p0 + pp;
        float hv = h[g];
        out0[g] = hv + (z - hv);  // straight-through: numerically z_q, rounded like ref
        float d = hv - z;
        lsum = fmaf(d, d, lsum);
    }
#pragma unroll
    for (int m = 32; m >= 1; m >>= 1) lsum += __shfl_xor(lsum, m, 64);
    if (lane == 0) wred[w] = lsum;
    __syncthreads();
    if (tid == 0) plsum[blockIdx.x] = wred[0] + wred[1] + wred[2] + wred[3];
}

// ---------------- kernel 3: final loss reduce ----------------
__global__ __launch_bounds__(256) void k_fin(const float* __restrict__ plsum,
                                             float* __restrict__ out2) {
    __shared__ float wred[4];
    const int tid = threadIdx.x;
    float s = plsum[tid] + plsum[tid + 256];
#pragma unroll
    for (int m = 32; m >= 1; m >>= 1) s += __shfl_xor(s, m, 64);
    if ((tid & 63) == 0) wred[tid >> 6] = s;
    __syncthreads();
    if (tid == 0) out2[0] = (wred[0] + wred[1] + wred[2] + wred[3]) * (1.0f / (float)N_OUT0);
}

extern "C" void kernel_launch(void* const* d_in, const int* in_sizes, int n_in,
                              void* d_out, int out_size, void* d_ws, size_t ws_size,
                              hipStream_t stream) {
    const float* h = (const float*)d_in[0];
    const float* emb = (const float*)d_in[1];
    float* out0 = (float*)d_out;                 // z_q_st  (4194304)
    float* out1 = out0 + N_OUT0;                 // indices (16384)
    float* out2 = out1 + NTOT;                   // commit_loss (1)

    // ws layout: esq f32[4096] | gbest u64[16384] | plsum f32[512]
    float* esq = (float*)d_ws;
    unsigned long long* gbest = (unsigned long long*)((char*)d_ws + 16384);
    float* plsum = (float*)((char*)d_ws + 16384 + 131072);

    hipLaunchKernelGGL(k_init, dim3(VOCAB), dim3(64), 0, stream, emb, esq, gbest);
    hipLaunchKernelGGL(k_argmin, dim3(1024), dim3(256), 0, stream, h, emb, esq, gbest);
    hipLaunchKernelGGL(k_gather, dim3(NTOT / 32), dim3(256), 0, stream, h, emb, gbest, out0, out1, plsum);
    hipLaunchKernelGGL(k_fin, dim3(1), dim3(256), 0, stream, plsum, out2);
}

// Round 2
// 216.058 us; speedup vs baseline: 2.2958x; 2.2958x over previous
//
#include <hip/hip_runtime.h>

#define D 256
#define VOCAB 4096
#define NTOT 16384      // 16 * 32 * 32
#define N_OUT0 4194304  // 16*256*32*32

typedef _Float16 half8 __attribute__((ext_vector_type(8)));
typedef float f32x4 __attribute__((ext_vector_type(4)));

__device__ __forceinline__ void gld16(const void* g, void* l) {
    __builtin_amdgcn_global_load_lds(
        (const __attribute__((address_space(1))) void*)g,
        (__attribute__((address_space(3))) void*)l, 16, 0, 0);
}

__device__ __forceinline__ unsigned long long pack_key(float d, int v) {
    unsigned u = __float_as_uint(d);
    u ^= ((unsigned)((int)u >> 31)) | 0x80000000u;  // monotonic float->uint
    return ((unsigned long long)u << 32) | (unsigned)v;
}

// ---------------- pack B: emb -> [4096][512] fp16 rows [hi(256)|lo(256)], esq, gbest init
__global__ __launch_bounds__(256) void k_pack_b(const float* __restrict__ emb,
                                                _Float16* __restrict__ Bp,
                                                float* __restrict__ esq,
                                                unsigned long long* __restrict__ gbest) {
    const int tid = threadIdx.x;
    const int w = tid >> 6, lane = tid & 63;
    const int v = blockIdx.x * 4 + w;
    float4 e = *(const float4*)(emb + (size_t)v * D + lane * 4);
    alignas(8) _Float16 hi[4], lo[4];
    float ef[4] = {e.x, e.y, e.z, e.w};
#pragma unroll
    for (int i = 0; i < 4; ++i) {
        hi[i] = (_Float16)ef[i];
        lo[i] = (_Float16)(ef[i] - (float)hi[i]);
    }
    _Float16* dst = Bp + ((size_t)v << 9) + lane * 4;
    *(float2*)dst = *(float2*)hi;
    *(float2*)(dst + 256) = *(float2*)lo;

    float s = e.x * e.x + e.y * e.y + e.z * e.z + e.w * e.w;
#pragma unroll
    for (int m = 32; m >= 1; m >>= 1) s += __shfl_xor(s, m, 64);
    if (lane == 0) esq[v] = s;
    if (tid < 16) gbest[blockIdx.x * 16 + tid] = ~0ULL;
}

// ---------------- pack A: h (B,C,P) -> [16384][512] fp16 rows [hi|lo]
__global__ __launch_bounds__(256) void k_pack_a(const float* __restrict__ h,
                                                _Float16* __restrict__ Ap) {
    const int tid = threadIdx.x;
    const int j = tid >> 4;   // c-group 0..15
    const int r = tid & 15;   // row within block
    const int n = blockIdx.x * 16 + r;
    const int b = n >> 10, p = n & 1023;
    const float* src = h + ((size_t)b << 18) + p;
    alignas(16) _Float16 hi[16], lo[16];
#pragma unroll
    for (int i = 0; i < 16; ++i) {
        float v = src[(size_t)(j * 16 + i) << 10];
        _Float16 hv = (_Float16)v;
        hi[i] = hv;
        lo[i] = (_Float16)(v - (float)hv);
    }
    _Float16* dst = Ap + ((size_t)n << 9) + j * 16;
    ((float4*)dst)[0] = ((float4*)hi)[0];
    ((float4*)dst)[1] = ((float4*)hi)[1];
    float4* dlo = (float4*)(dst + 256);
    dlo[0] = ((float4*)lo)[0];
    dlo[1] = ((float4*)lo)[1];
}

// ---------------- distance GEMM (split-fp16 MFMA, K=3x256) + argmin ----------------
// grid 4096: bm = bidx>>5 (128 m-tiles of 128), bn = bidx&31 (32 v-tiles of 128)
__global__ __launch_bounds__(256, 2) void k_argmin_mfma(const _Float16* __restrict__ Ap,
                                                        const _Float16* __restrict__ Bp,
                                                        const float* __restrict__ esq,
                                                        unsigned long long* __restrict__ gbest) {
    __shared__ _Float16 As[128 * 32];
    __shared__ _Float16 Bs[128 * 32];
    __shared__ unsigned long long red[128];

    const int tid = threadIdx.x;
    const int bm = blockIdx.x >> 5;
    const int bn = blockIdx.x & 31;
    const int m0 = bm * 128, n0 = bn * 128;

    if (tid < 128) red[tid] = ~0ULL;

    const int w = tid >> 6, l = tid & 63;
    const int wm = w & 1, wn = w >> 1;
    const int quad = l >> 4, j16 = l & 15;

    f32x4 acc[4][4];
#pragma unroll
    for (int i = 0; i < 4; ++i)
#pragma unroll
        for (int jj = 0; jj < 4; ++jj) acc[i][jj] = (f32x4)0.0f;

    // staging: thread loads 16B: row = tid>>2 (0..63), byte col = (tid&3)*16; two insts per tile
    const int srow = tid >> 2;
    const int scol = (tid & 3) << 4;
    const char* Ab = (const char*)Ap + (((size_t)(m0 + srow)) << 10) + scol;
    const char* Bb = (const char*)Bp + (((size_t)(n0 + srow)) << 10) + scol;
    _Float16* As0 = As + srow * 32 + (scol >> 1);  // = As + tid*8 elems
    _Float16* Bs0 = Bs + srow * 32 + (scol >> 1);

    const _Float16* aRd = As + (wm * 64 + j16) * 32 + quad * 8;
    const _Float16* bRd = Bs + (wn * 64 + j16) * 32 + quad * 8;

    for (int kc = 0; kc < 24; ++kc) {
        const int g = kc >> 3, rr = kc & 7;
        const int aoff = ((g == 2) ? 512 : 0) + rr * 64;  // bytes within 1024B row
        const int boff = ((g == 1) ? 512 : 0) + rr * 64;
        gld16(Ab + aoff, As0);
        gld16(Ab + 65536 + aoff, As0 + 2048);
        gld16(Bb + boff, Bs0);
        gld16(Bb + 65536 + boff, Bs0 + 2048);
        __syncthreads();
        half8 af[4], bf[4];
#pragma unroll
        for (int mt = 0; mt < 4; ++mt) af[mt] = *(const half8*)(aRd + mt * 16 * 32);
#pragma unroll
        for (int nt = 0; nt < 4; ++nt) bf[nt] = *(const half8*)(bRd + nt * 16 * 32);
#pragma unroll
        for (int mt = 0; mt < 4; ++mt)
#pragma unroll
            for (int nt = 0; nt < 4; ++nt)
                acc[mt][nt] = __builtin_amdgcn_mfma_f32_16x16x32_f16(af[mt], bf[nt], acc[mt][nt], 0, 0, 0);
        __syncthreads();
    }

    // epilogue: dist = esq[v] - 2*dot (||h||^2 constant per row, argmin-invariant)
    float es[4];
#pragma unroll
    for (int nt = 0; nt < 4; ++nt) es[nt] = esq[n0 + wn * 64 + nt * 16 + j16];
#pragma unroll
    for (int mt = 0; mt < 4; ++mt) {
#pragma unroll
        for (int r = 0; r < 4; ++r) {
            unsigned long long best = ~0ULL;
#pragma unroll
            for (int nt = 0; nt < 4; ++nt) {
                float dv = es[nt] - 2.0f * acc[mt][nt][r];
                unsigned long long key = pack_key(dv, n0 + wn * 64 + nt * 16 + j16);
                best = key < best ? key : best;
            }
#pragma unroll
            for (int m = 8; m >= 1; m >>= 1) {
                unsigned long long o = __shfl_xor(best, m, 64);
                best = o < best ? o : best;
            }
            if (j16 == 0) atomicMin(&red[wm * 64 + mt * 16 + quad * 4 + r], best);
        }
    }
    __syncthreads();
    if (tid < 128) atomicMin(&gbest[m0 + tid], red[tid]);
}

// ---------------- fallback fp32 path (used only if ws too small) ----------------
__global__ __launch_bounds__(64) void k_init(const float* __restrict__ emb,
                                             float* __restrict__ esq,
                                             unsigned long long* __restrict__ gbest) {
    const int v = blockIdx.x;
    const int lane = threadIdx.x;
    float4 e = *(const float4*)(emb + (size_t)v * D + lane * 4);
    float s = e.x * e.x + e.y * e.y + e.z * e.z + e.w * e.w;
#pragma unroll
    for (int m = 32; m >= 1; m >>= 1) s += __shfl_xor(s, m, 64);
    if (lane == 0) esq[v] = s;
    if (blockIdx.x < NTOT / 64) gbest[blockIdx.x * 64 + lane] = 0xFFFFFFFFFFFFFFFFULL;
}

__global__ __launch_bounds__(256) void k_argmin_f32(const float* __restrict__ h,
                                                    const float* __restrict__ emb,
                                                    const float* __restrict__ esq,
                                                    unsigned long long* __restrict__ gbest) {
    __shared__ float hT[16][64];
    __shared__ float eT[16][256];
    __shared__ unsigned long long red[64];
    const int tid = threadIdx.x;
    const int nt = blockIdx.x >> 2;
    const int vs = blockIdx.x & 3;
    const int n0 = nt * 64;
    const int b = n0 >> 10;
    const int p0 = n0 & 1023;
    const float* hb = h + (((size_t)b * D) << 10) + p0;
    const int tn = tid & 7;
    const int tv = tid >> 3;
    float minv[8]; int mini[8];
#pragma unroll
    for (int i = 0; i < 8; ++i) { minv[i] = 3.0e38f; mini[i] = 0; }
    const int scc = tid >> 4;
    const int snn = (tid * 4) & 63;
    for (int vc = 0; vc < 4; ++vc) {
        const int v0 = vs * 1024 + vc * 256;
        float acc[8][8];
#pragma unroll
        for (int i = 0; i < 8; ++i)
#pragma unroll
            for (int j = 0; j < 8; ++j) acc[i][j] = 0.0f;
        for (int c0 = 0; c0 < D; c0 += 16) {
            float4 hv4 = *(const float4*)(hb + (size_t)(c0 + scc) * 1024 + snn);
            const float* er = emb + (size_t)(v0 + tid) * D + c0;
            float4 e0 = *(const float4*)(er);
            float4 e1 = *(const float4*)(er + 4);
            float4 e2 = *(const float4*)(er + 8);
            float4 e3 = *(const float4*)(er + 12);
            *(float4*)&hT[scc][snn] = hv4;
            eT[0][tid] = e0.x;  eT[1][tid] = e0.y;  eT[2][tid] = e0.z;  eT[3][tid] = e0.w;
            eT[4][tid] = e1.x;  eT[5][tid] = e1.y;  eT[6][tid] = e1.z;  eT[7][tid] = e1.w;
            eT[8][tid] = e2.x;  eT[9][tid] = e2.y;  eT[10][tid] = e2.z; eT[11][tid] = e2.w;
            eT[12][tid] = e3.x; eT[13][tid] = e3.y; eT[14][tid] = e3.z; eT[15][tid] = e3.w;
            __syncthreads();
#pragma unroll
            for (int cc = 0; cc < 16; ++cc) {
                float4 a0 = *(const float4*)&hT[cc][tn * 8];
                float4 a1 = *(const float4*)&hT[cc][tn * 8 + 4];
                float4 b0 = *(const float4*)&eT[cc][tv * 8];
                float4 b1 = *(const float4*)&eT[cc][tv * 8 + 4];
                float av[8] = {a0.x, a0.y, a0.z, a0.w, a1.x, a1.y, a1.z, a1.w};
                float bv[8] = {b0.x, b0.y, b0.z, b0.w, b1.x, b1.y, b1.z, b1.w};
#pragma unroll
                for (int i = 0; i < 8; ++i)
#pragma unroll
                    for (int j = 0; j < 8; ++j)
                        acc[i][j] = fmaf(av[i], bv[j], acc[i][j]);
            }
            __syncthreads();
        }
#pragma unroll
        for (int j = 0; j < 8; ++j) {
            int v = v0 + tv * 8 + j;
            float es = esq[v];
#pragma unroll
            for (int i = 0; i < 8; ++i) {
                float dv = es - 2.0f * acc[i][j];
                if (dv < minv[i]) { minv[i] = dv; mini[i] = v; }
            }
        }
    }
    if (tid < 64) red[tid] = 0xFFFFFFFFFFFFFFFFULL;
    __syncthreads();
#pragma unroll
    for (int i = 0; i < 8; ++i) {
        unsigned long long key = pack_key(minv[i], mini[i]);
        atomicMin(&red[tn * 8 + i], key);
    }
    __syncthreads();
    if (tid < 64) atomicMin(&gbest[n0 + tid], red[tid]);
}

// ---------------- gather z_q, outputs, loss partials ----------------
__global__ __launch_bounds__(256) void k_gather(const float* __restrict__ h,
                                                const float* __restrict__ emb,
                                                const unsigned long long* __restrict__ gbest,
                                                float* __restrict__ out0,
                                                float* __restrict__ out1,
                                                float* __restrict__ plsum) {
    __shared__ float zq[32][260];
    __shared__ float wred[4];
    const int tid = threadIdx.x;
    const int lane = tid & 63;
    const int w = tid >> 6;
    const int n0 = blockIdx.x * 32;
    const int b = n0 >> 10;
    const int p0 = n0 & 1023;
#pragma unroll
    for (int rr = 0; rr < 8; ++rr) {
        int r = w * 8 + rr;
        unsigned idx = (unsigned)(gbest[n0 + r] & 0xFFFFFFFFULL);
        float4 e4 = *(const float4*)(emb + (size_t)idx * D + lane * 4);
        *(float4*)&zq[r][lane * 4] = e4;
    }
    if (tid < 32) {
        unsigned idx = (unsigned)(gbest[n0 + tid] & 0xFFFFFFFFULL);
        out1[n0 + tid] = (float)idx;
    }
    __syncthreads();
    float lsum = 0.0f;
    const size_t base = ((size_t)b * D) << 10;
#pragma unroll 4
    for (int it = 0; it < 32; ++it) {
        int c = it * 8 + (tid >> 5);
        int pp = tid & 31;
        float z = zq[pp][c];
        size_t g = base + ((size_t)c << 10) + p0 + pp;
        float hv = h[g];
        out0[g] = hv + (z - hv);
        float d = hv - z;
        lsum = fmaf(d, d, lsum);
    }
#pragma unroll
    for (int m = 32; m >= 1; m >>= 1) lsum += __shfl_xor(lsum, m, 64);
    if (lane == 0) wred[w] = lsum;
    __syncthreads();
    if (tid == 0) plsum[blockIdx.x] = wred[0] + wred[1] + wred[2] + wred[3];
}

__global__ __launch_bounds__(256) void k_fin(const float* __restrict__ plsum,
                                             float* __restrict__ out2) {
    __shared__ float wred[4];
    const int tid = threadIdx.x;
    float s = plsum[tid] + plsum[tid + 256];
#pragma unroll
    for (int m = 32; m >= 1; m >>= 1) s += __shfl_xor(s, m, 64);
    if ((tid & 63) == 0) wred[tid >> 6] = s;
    __syncthreads();
    if (tid == 0) out2[0] = (wred[0] + wred[1] + wred[2] + wred[3]) * (1.0f / (float)N_OUT0);
}

extern "C" void kernel_launch(void* const* d_in, const int* in_sizes, int n_in,
                              void* d_out, int out_size, void* d_ws, size_t ws_size,
                              hipStream_t stream) {
    const float* h = (const float*)d_in[0];
    const float* emb = (const float*)d_in[1];
    float* out0 = (float*)d_out;
    float* out1 = out0 + N_OUT0;
    float* out2 = out1 + NTOT;

    const size_t NEED = 16777216ull + 4194304ull + 16384ull + 131072ull + 2048ull;
    if (ws_size >= NEED) {
        _Float16* Ap = (_Float16*)d_ws;
        _Float16* Bp = (_Float16*)((char*)d_ws + 16777216);
        float* esq = (float*)((char*)d_ws + 16777216 + 4194304);
        unsigned long long* gbest = (unsigned long long*)((char*)d_ws + 16777216 + 4194304 + 16384);
        float* plsum = (float*)((char*)d_ws + 16777216 + 4194304 + 16384 + 131072);
        hipLaunchKernelGGL(k_pack_b, dim3(VOCAB / 4), dim3(256), 0, stream, emb, Bp, esq, gbest);
        hipLaunchKernelGGL(k_pack_a, dim3(NTOT / 16), dim3(256), 0, stream, h, Ap);
        hipLaunchKernelGGL(k_argmin_mfma, dim3(4096), dim3(256), 0, stream, Ap, Bp, esq, gbest);
        hipLaunchKernelGGL(k_gather, dim3(NTOT / 32), dim3(256), 0, stream, h, emb, gbest, out0, out1, plsum);
        hipLaunchKernelGGL(k_fin, dim3(1), dim3(256), 0, stream, plsum, out2);
    } else {
        float* esq = (float*)d_ws;
        unsigned long long* gbest = (unsigned long long*)((char*)d_ws + 16384);
        float* plsum = (float*)((char*)d_ws + 16384 + 131072);
        hipLaunchKernelGGL(k_init, dim3(VOCAB), dim3(64), 0, stream, emb, esq, gbest);
        hipLaunchKernelGGL(k_argmin_f32, dim3(1024), dim3(256), 0, stream, h, emb, esq, gbest);
        hipLaunchKernelGGL(k_gather, dim3(NTOT / 32), dim3(256), 0, stream, h, emb, gbest, out0, out1, plsum);
        hipLaunchKernelGGL(k_fin, dim3(1), dim3(256), 0, stream, plsum, out2);
    }
}

// Round 3
// 201.694 us; speedup vs baseline: 2.4593x; 1.0712x over previous
//
#include <hip/hip_runtime.h>

#define D 256
#define VOCAB 4096
#define NTOT 16384      // 16 * 32 * 32
#define N_OUT0 4194304  // 16*256*32*32

typedef _Float16 half8 __attribute__((ext_vector_type(8)));
typedef float f32x4 __attribute__((ext_vector_type(4)));

__device__ __forceinline__ void gld16(const void* g, void* l) {
    __builtin_amdgcn_global_load_lds(
        (const __attribute__((address_space(1))) void*)g,
        (__attribute__((address_space(3))) void*)l, 16, 0, 0);
}

__device__ __forceinline__ unsigned long long pack_key(float d, int v) {
    unsigned u = __float_as_uint(d);
    u ^= ((unsigned)((int)u >> 31)) | 0x80000000u;  // monotonic float->uint
    return ((unsigned long long)u << 32) | (unsigned)v;
}

// ---------------- prep: esq, gbest init, out2 zero ----------------
__global__ __launch_bounds__(64) void k_prep(const float* __restrict__ emb,
                                             float* __restrict__ esq,
                                             unsigned long long* __restrict__ gbest,
                                             float* __restrict__ out2) {
    const int v = blockIdx.x, lane = threadIdx.x;
    float4 e = *(const float4*)(emb + (size_t)v * D + lane * 4);
    float s = e.x * e.x + e.y * e.y + e.z * e.z + e.w * e.w;
#pragma unroll
    for (int m = 32; m >= 1; m >>= 1) s += __shfl_xor(s, m, 64);
    if (lane == 0) esq[v] = s;
    if (v < NTOT / 64) gbest[(size_t)v * 64 + lane] = ~0ULL;
    if (v == 0 && lane == 0) out2[0] = 0.0f;
}

// ---------------- fused pack: A (blocks 0..511) and B (512..767) ----------------
// Apk layout (halfs): [bm 64][w 8][hl 2][q 4][r 256][j 8]  tile-window = 16384 halfs
// Bpk layout (halfs): [bn 32][w 8][hl 2][q 4][r 128][j 8]  tile-window = 8192 halfs
__global__ __launch_bounds__(256) void k_pack(const float* __restrict__ h,
                                              const float* __restrict__ emb,
                                              _Float16* __restrict__ Apk,
                                              _Float16* __restrict__ Bpk) {
    __shared__ float S[8192];
    const int tid = threadIdx.x;
    const int bid = blockIdx.x;
    if (bid < 512) {
        const int bm = bid >> 3, w = bid & 7;
        const int b = bm >> 2, p0 = (bm & 3) * 256;
        const float* src = h + ((size_t)b << 18) + p0;
        // fill: S[cl*256 + r] = h[b][w*32+cl][p0+r], coalesced 1KB rows
#pragma unroll 4
        for (int cl = 0; cl < 32; ++cl)
            S[cl * 256 + tid] = src[(size_t)(w * 32 + cl) << 10 | (unsigned)tid];
        __syncthreads();
        _Float16* dstT = Apk + (size_t)bm * 131072 + (size_t)w * 16384;
#pragma unroll
        for (int i = 0; i < 4; ++i) {  // q = i, r = tid
            alignas(16) _Float16 hi[8], lo[8];
#pragma unroll
            for (int j = 0; j < 8; ++j) {
                float vv = S[(i * 8 + j) * 256 + tid];
                _Float16 hv = (_Float16)vv;
                hi[j] = hv;
                lo[j] = (_Float16)(vv - (float)hv);
            }
            _Float16* dst = dstT + i * 2048 + tid * 8;
            *(half8*)dst = *(half8*)hi;
            *(half8*)(dst + 8192) = *(half8*)lo;
        }
    } else {
        const int bid2 = bid - 512;
        const int bn = bid2 >> 3, w = bid2 & 7;
        const int v0 = bn * 128;
        // fill: S[cl*129 + r] = emb[v0+r][w*32+cl]
#pragma unroll 4
        for (int i = 0; i < 16; ++i) {
            int flat = i * 256 + tid;
            int r = flat >> 5, cl = flat & 31;
            S[cl * 129 + r] = emb[(size_t)(v0 + r) * D + w * 32 + cl];
        }
        __syncthreads();
        _Float16* dstT = Bpk + (size_t)bn * 65536 + (size_t)w * 8192;
#pragma unroll
        for (int i = 0; i < 2; ++i) {
            int s = i * 256 + tid;
            int q = s >> 7, r = s & 127;
            alignas(16) _Float16 hi[8], lo[8];
#pragma unroll
            for (int j = 0; j < 8; ++j) {
                float vv = S[(q * 8 + j) * 129 + r];
                _Float16 hv = (_Float16)vv;
                hi[j] = hv;
                lo[j] = (_Float16)(vv - (float)hv);
            }
            _Float16* dst = dstT + q * 1024 + r * 8;
            *(half8*)dst = *(half8*)hi;
            *(half8*)(dst + 4096) = *(half8*)lo;
        }
    }
}

// ---------------- distance GEMM (split-fp16, window-resident) + argmin ----------------
// grid 2048: bm = bid>>5 (64 tiles of 256 m), bn = bid&31 (32 tiles of 128 v)
// 4 waves as 2x2; wave tile 128m x 64v = 8x4 of 16x16x32 MFMA
__global__ __launch_bounds__(256, 2) void k_gemm(const _Float16* __restrict__ Apk,
                                                 const _Float16* __restrict__ Bpk,
                                                 const float* __restrict__ esq,
                                                 unsigned long long* __restrict__ gbest) {
    __shared__ _Float16 As[16384];  // [hl]8192 + [q]2048 + [r]8
    __shared__ _Float16 Bs[8192];   // [hl]4096 + [q]1024 + [r]8
    __shared__ unsigned long long red[256];

    const int tid = threadIdx.x;
    const int bm = blockIdx.x >> 5, bn = blockIdx.x & 31;
    const int m0 = bm * 256, n0 = bn * 128;
    red[tid] = ~0ULL;

    const int wv = tid >> 6, l = tid & 63;
    const int wm = wv & 1, wn = wv >> 1;
    const int quad = l >> 4, j16 = l & 15;

    f32x4 acc[8][4];
#pragma unroll
    for (int i = 0; i < 8; ++i)
#pragma unroll
        for (int j = 0; j < 4; ++j) acc[i][j] = (f32x4)0.0f;

    const _Float16* Aw0 = Apk + (size_t)bm * 131072;
    const _Float16* Bw0 = Bpk + (size_t)bn * 65536;
    const _Float16* aBase = As + quad * 2048 + (wm * 128 + j16) * 8;
    const _Float16* bBase = Bs + quad * 1024 + (wn * 64 + j16) * 8;

    for (int w = 0; w < 8; ++w) {
        const _Float16* Aw = Aw0 + w * 16384;
        const _Float16* Bw = Bw0 + w * 8192;
#pragma unroll
        for (int i = 0; i < 8; ++i) gld16(Aw + i * 2048 + tid * 8, As + i * 2048 + tid * 8);
#pragma unroll
        for (int i = 0; i < 4; ++i) gld16(Bw + i * 2048 + tid * 8, Bs + i * 2048 + tid * 8);
        __syncthreads();

        half8 af[8], bf[4];
        // pass 1: hiA . loB
#pragma unroll
        for (int mt = 0; mt < 8; ++mt) af[mt] = *(const half8*)(aBase + mt * 128);
#pragma unroll
        for (int nt = 0; nt < 4; ++nt) bf[nt] = *(const half8*)(bBase + 4096 + nt * 128);
#pragma unroll
        for (int mt = 0; mt < 8; ++mt)
#pragma unroll
            for (int nt = 0; nt < 4; ++nt)
                acc[mt][nt] = __builtin_amdgcn_mfma_f32_16x16x32_f16(af[mt], bf[nt], acc[mt][nt], 0, 0, 0);
        // pass 2: hiA . hiB (reuse af)
#pragma unroll
        for (int nt = 0; nt < 4; ++nt) bf[nt] = *(const half8*)(bBase + nt * 128);
#pragma unroll
        for (int mt = 0; mt < 8; ++mt)
#pragma unroll
            for (int nt = 0; nt < 4; ++nt)
                acc[mt][nt] = __builtin_amdgcn_mfma_f32_16x16x32_f16(af[mt], bf[nt], acc[mt][nt], 0, 0, 0);
        // pass 3: loA . hiB (reuse bf)
#pragma unroll
        for (int mt = 0; mt < 8; ++mt) af[mt] = *(const half8*)(aBase + 8192 + mt * 128);
#pragma unroll
        for (int mt = 0; mt < 8; ++mt)
#pragma unroll
            for (int nt = 0; nt < 4; ++nt)
                acc[mt][nt] = __builtin_amdgcn_mfma_f32_16x16x32_f16(af[mt], bf[nt], acc[mt][nt], 0, 0, 0);
        __syncthreads();
    }

    // epilogue: dist = esq[v] - 2*dot; argmin with first-index tie-break
    float es[4];
#pragma unroll
    for (int nt = 0; nt < 4; ++nt) es[nt] = esq[n0 + wn * 64 + nt * 16 + j16];
#pragma unroll
    for (int mt = 0; mt < 8; ++mt) {
#pragma unroll
        for (int r = 0; r < 4; ++r) {
            unsigned long long best = ~0ULL;
#pragma unroll
            for (int nt = 0; nt < 4; ++nt) {
                float dv = es[nt] - 2.0f * acc[mt][nt][r];
                unsigned long long key = pack_key(dv, n0 + wn * 64 + nt * 16 + j16);
                best = key < best ? key : best;
            }
#pragma unroll
            for (int m = 8; m >= 1; m >>= 1) {
                unsigned long long o = __shfl_xor(best, m, 64);
                best = o < best ? o : best;
            }
            if (j16 == 0) atomicMin(&red[wm * 128 + mt * 16 + quad * 4 + r], best);
        }
    }
    __syncthreads();
    atomicMin(&gbest[m0 + tid], red[tid]);
}

// ---------------- gather z_q, outputs, loss (atomic) ----------------
__global__ __launch_bounds__(256) void k_gather(const float* __restrict__ h,
                                                const float* __restrict__ emb,
                                                const unsigned long long* __restrict__ gbest,
                                                float* __restrict__ out0,
                                                float* __restrict__ out1,
                                                float* __restrict__ out2) {
    __shared__ float zq[32][260];
    __shared__ float wred[4];
    const int tid = threadIdx.x;
    const int lane = tid & 63;
    const int w = tid >> 6;
    const int n0 = blockIdx.x * 32;
    const int b = n0 >> 10;
    const int p0 = n0 & 1023;
#pragma unroll
    for (int rr = 0; rr < 8; ++rr) {
        int r = w * 8 + rr;
        unsigned idx = (unsigned)(gbest[n0 + r] & 0xFFFFFFFFULL);
        float4 e4 = *(const float4*)(emb + (size_t)idx * D + lane * 4);
        *(float4*)&zq[r][lane * 4] = e4;
    }
    if (tid < 32) {
        unsigned idx = (unsigned)(gbest[n0 + tid] & 0xFFFFFFFFULL);
        out1[n0 + tid] = (float)idx;
    }
    __syncthreads();
    float lsum = 0.0f;
    const size_t base = ((size_t)b * D) << 10;
#pragma unroll 4
    for (int it = 0; it < 32; ++it) {
        int c = it * 8 + (tid >> 5);
        int pp = tid & 31;
        float z = zq[pp][c];
        size_t g = base + ((size_t)c << 10) + p0 + pp;
        float hv = h[g];
        out0[g] = hv + (z - hv);
        float d = hv - z;
        lsum = fmaf(d, d, lsum);
    }
#pragma unroll
    for (int m = 32; m >= 1; m >>= 1) lsum += __shfl_xor(lsum, m, 64);
    if (lane == 0) wred[w] = lsum;
    __syncthreads();
    if (tid == 0)
        atomicAdd(out2, (wred[0] + wred[1] + wred[2] + wred[3]) * (1.0f / (float)N_OUT0));
}

extern "C" void kernel_launch(void* const* d_in, const int* in_sizes, int n_in,
                              void* d_out, int out_size, void* d_ws, size_t ws_size,
                              hipStream_t stream) {
    const float* h = (const float*)d_in[0];
    const float* emb = (const float*)d_in[1];
    float* out0 = (float*)d_out;
    float* out1 = out0 + N_OUT0;
    float* out2 = out1 + NTOT;

    // ws: Apk 16MB | Bpk 4MB | esq 16KB | gbest 128KB   (R2 confirmed ws >= 21.1MB)
    _Float16* Apk = (_Float16*)d_ws;
    _Float16* Bpk = (_Float16*)((char*)d_ws + 16777216);
    float* esq = (float*)((char*)d_ws + 16777216 + 4194304);
    unsigned long long* gbest = (unsigned long long*)((char*)d_ws + 16777216 + 4194304 + 16384);

    hipLaunchKernelGGL(k_prep, dim3(VOCAB), dim3(64), 0, stream, emb, esq, gbest, out2);
    hipLaunchKernelGGL(k_pack, dim3(768), dim3(256), 0, stream, h, emb, Apk, Bpk);
    hipLaunchKernelGGL(k_gemm, dim3(2048), dim3(256), 0, stream, Apk, Bpk, esq, gbest);
    hipLaunchKernelGGL(k_gather, dim3(NTOT / 32), dim3(256), 0, stream, h, emb, gbest, out0, out1, out2);
}